// Round 1
// baseline (970.381 us; speedup 1.0000x reference)
//
#include <hip/hip_runtime.h>
#include <hip/hip_bf16.h>
#include <stdint.h>

#define NEXP 8
#define NROWS 8192
#define HID 2048
#define INTERN 2048
#define CAP 8192
#define TOTSLOT (NROWS * 2)

typedef __attribute__((ext_vector_type(4))) float f32x4;
typedef __attribute__((ext_vector_type(8))) short bf16x8;

__device__ __forceinline__ unsigned short f2bf(float f) {
  union { float f; uint32_t u; } v; v.f = f;
  uint32_t u = v.u;
  uint32_t r = (u + 0x7fffu + ((u >> 16) & 1u)) >> 16;
  return (unsigned short)r;
}

// ---------------- router: top-2 of 8, renormalize, bucket per expert ----------------
__global__ void router_kernel(const float* __restrict__ probs,
                              int* __restrict__ cnt,
                              int* __restrict__ brow,
                              float* __restrict__ bw) {
  int row = blockIdx.x * blockDim.x + threadIdx.x;
  if (row >= NROWS) return;
  float p[8];
#pragma unroll
  for (int j = 0; j < 8; j++) p[j] = probs[row * 8 + j];
  int i1 = 0; float v1 = p[0];
#pragma unroll
  for (int j = 1; j < 8; j++) if (p[j] > v1) { v1 = p[j]; i1 = j; }
  int i2 = -1; float v2 = -1e30f;
#pragma unroll
  for (int j = 0; j < 8; j++) if (j != i1 && p[j] > v2) { v2 = p[j]; i2 = j; }
  float s = v1 + v2;
  float w1 = v1 / s, w2 = v2 / s;
  int pos1 = atomicAdd(&cnt[i1], 1);
  brow[i1 * CAP + pos1] = row; bw[i1 * CAP + pos1] = w1;
  int pos2 = atomicAdd(&cnt[i2], 1);
  brow[i2 * CAP + pos2] = row; bw[i2 * CAP + pos2] = w2;
}

__global__ void offsets_kernel(const int* __restrict__ cnt, int* __restrict__ ofs) {
  if (threadIdx.x == 0 && blockIdx.x == 0) {
    int a = 0;
    for (int e = 0; e < NEXP; e++) { ofs[e] = a; a += cnt[e]; }
  }
}

// ---------------- transpose+cast: [E][K][N] f32 -> [E][N][K] bf16 ----------------
__global__ void transpose_cast_kernel(const float* __restrict__ src,
                                      unsigned short* __restrict__ dst) {
  __shared__ float tile[32][33];
  int e = blockIdx.z;
  int k0 = blockIdx.y * 32;
  int n0 = blockIdx.x * 32;
  const float* s = src + (size_t)e * HID * INTERN;
  unsigned short* d = dst + (size_t)e * HID * INTERN;
  int t = threadIdx.x;
  int r = t >> 3;          // 0..31
  int c4 = (t & 7) * 4;    // 0..28 step 4
  float4 v = *reinterpret_cast<const float4*>(s + (size_t)(k0 + r) * 2048 + n0 + c4);
  tile[r][c4 + 0] = v.x; tile[r][c4 + 1] = v.y;
  tile[r][c4 + 2] = v.z; tile[r][c4 + 3] = v.w;
  __syncthreads();
  ushort4 o;
  o.x = f2bf(tile[c4 + 0][r]);
  o.y = f2bf(tile[c4 + 1][r]);
  o.z = f2bf(tile[c4 + 2][r]);
  o.w = f2bf(tile[c4 + 3][r]);
  *reinterpret_cast<ushort4*>(d + (size_t)(n0 + r) * 2048 + k0 + c4) = o;
}

// ---------------- GEMM1: h1 = Xe@fc1, h3 = Xe@fc3, act = silu(h1)*h3 (bf16) ----------------
__global__ __launch_bounds__(256, 2)
void gemm1_kernel(const float* __restrict__ x,
                  const unsigned short* __restrict__ wt1,   // [E][N][K] bf16
                  const unsigned short* __restrict__ wt3,
                  const int* __restrict__ cnt, const int* __restrict__ ofs,
                  const int* __restrict__ brow,
                  unsigned short* __restrict__ act) {
  const int e = blockIdx.z, mt = blockIdx.y, nt = blockIdx.x;
  const int Me = cnt[e];
  if (mt * 128 >= Me) return;
  __shared__ unsigned short As[128][40];
  __shared__ unsigned short B1s[128][40];
  __shared__ unsigned short B3s[128][40];
  __shared__ int ridx[128];
  const int t = threadIdx.x;
  const int lane = t & 63, wave = t >> 6;
  if (t < 128) {
    int sl = mt * 128 + t;
    ridx[t] = (sl < Me) ? brow[e * CAP + sl] : 0;
  }
  const int wm = wave >> 1, wn = wave & 1;
  const int l15 = lane & 15, kq = lane >> 4;
  const unsigned short* w1 = wt1 + (size_t)e * HID * INTERN + (size_t)(nt * 128) * HID;
  const unsigned short* w3 = wt3 + (size_t)e * HID * INTERN + (size_t)(nt * 128) * HID;
  f32x4 acc1[4][4] = {};
  f32x4 acc3[4][4] = {};
  const int arow = t >> 1;
  const int acol = (t & 1) * 16;
  __syncthreads();  // ridx ready

  for (int k0 = 0; k0 < HID; k0 += 32) {
    // global loads into regs
    const float* xp = x + (size_t)ridx[arow] * HID + k0 + acol;
    float4 a0 = *reinterpret_cast<const float4*>(xp + 0);
    float4 a1 = *reinterpret_cast<const float4*>(xp + 4);
    float4 a2 = *reinterpret_cast<const float4*>(xp + 8);
    float4 a3 = *reinterpret_cast<const float4*>(xp + 12);
    const unsigned short* b1p = w1 + (size_t)arow * HID + k0 + acol;
    const unsigned short* b3p = w3 + (size_t)arow * HID + k0 + acol;
    int4 b1a = *reinterpret_cast<const int4*>(b1p);
    int4 b1b = *reinterpret_cast<const int4*>(b1p + 8);
    int4 b3a = *reinterpret_cast<const int4*>(b3p);
    int4 b3b = *reinterpret_cast<const int4*>(b3p + 8);

    unsigned short ua[16];
    ua[0] = f2bf(a0.x); ua[1] = f2bf(a0.y); ua[2] = f2bf(a0.z); ua[3] = f2bf(a0.w);
    ua[4] = f2bf(a1.x); ua[5] = f2bf(a1.y); ua[6] = f2bf(a1.z); ua[7] = f2bf(a1.w);
    ua[8] = f2bf(a2.x); ua[9] = f2bf(a2.y); ua[10] = f2bf(a2.z); ua[11] = f2bf(a2.w);
    ua[12] = f2bf(a3.x); ua[13] = f2bf(a3.y); ua[14] = f2bf(a3.z); ua[15] = f2bf(a3.w);

    __syncthreads();  // prior iter's LDS reads done
    *reinterpret_cast<int4*>(&As[arow][acol + 0]) = *reinterpret_cast<const int4*>(&ua[0]);
    *reinterpret_cast<int4*>(&As[arow][acol + 8]) = *reinterpret_cast<const int4*>(&ua[8]);
    *reinterpret_cast<int4*>(&B1s[arow][acol + 0]) = b1a;
    *reinterpret_cast<int4*>(&B1s[arow][acol + 8]) = b1b;
    *reinterpret_cast<int4*>(&B3s[arow][acol + 0]) = b3a;
    *reinterpret_cast<int4*>(&B3s[arow][acol + 8]) = b3b;
    __syncthreads();

    bf16x8 af[4], bf1[4], bf3[4];
#pragma unroll
    for (int i = 0; i < 4; i++)
      af[i] = *reinterpret_cast<const bf16x8*>(&As[wm * 64 + i * 16 + l15][kq * 8]);
#pragma unroll
    for (int i = 0; i < 4; i++)
      bf1[i] = *reinterpret_cast<const bf16x8*>(&B1s[wn * 64 + i * 16 + l15][kq * 8]);
#pragma unroll
    for (int i = 0; i < 4; i++)
      bf3[i] = *reinterpret_cast<const bf16x8*>(&B3s[wn * 64 + i * 16 + l15][kq * 8]);
#pragma unroll
    for (int mi = 0; mi < 4; mi++)
#pragma unroll
      for (int ni = 0; ni < 4; ni++) {
        acc1[mi][ni] = __builtin_amdgcn_mfma_f32_16x16x32_bf16(af[mi], bf1[ni], acc1[mi][ni], 0, 0, 0);
        acc3[mi][ni] = __builtin_amdgcn_mfma_f32_16x16x32_bf16(af[mi], bf3[ni], acc3[mi][ni], 0, 0, 0);
      }
  }

  const int slot0 = ofs[e] + mt * 128;
#pragma unroll
  for (int mi = 0; mi < 4; mi++) {
#pragma unroll
    for (int ni = 0; ni < 4; ni++) {
      int coln = nt * 128 + wn * 64 + ni * 16 + l15;
#pragma unroll
      for (int r = 0; r < 4; r++) {
        int lrow = wm * 64 + mi * 16 + kq * 4 + r;
        if (mt * 128 + lrow < Me) {
          float h1 = acc1[mi][ni][r];
          float h3 = acc3[mi][ni][r];
          float sig = 1.f / (1.f + __expf(-h1));
          act[(size_t)(slot0 + lrow) * INTERN + coln] = f2bf(h1 * sig * h3);
        }
      }
    }
  }
}

// ---------------- GEMM2: out[row] += w * (act @ fc2) ----------------
__global__ __launch_bounds__(256, 2)
void gemm2_kernel(const unsigned short* __restrict__ act,
                  const unsigned short* __restrict__ wt2,   // [E][N=hid][K=inter] bf16
                  const int* __restrict__ cnt, const int* __restrict__ ofs,
                  const int* __restrict__ brow, const float* __restrict__ bw,
                  float* __restrict__ out) {
  const int e = blockIdx.z, mt = blockIdx.y, nt = blockIdx.x;
  const int Me = cnt[e];
  if (mt * 128 >= Me) return;
  __shared__ unsigned short As[128][40];
  __shared__ unsigned short Bs[128][40];
  __shared__ int ridx[128];
  __shared__ float rww[128];
  const int t = threadIdx.x;
  const int lane = t & 63, wave = t >> 6;
  if (t < 128) {
    int sl = mt * 128 + t;
    ridx[t] = (sl < Me) ? brow[e * CAP + sl] : 0;
    rww[t] = (sl < Me) ? bw[e * CAP + sl] : 0.f;
  }
  const int wm = wave >> 1, wn = wave & 1;
  const int l15 = lane & 15, kq = lane >> 4;
  const int arow = t >> 1;
  const int acol = (t & 1) * 16;
  int aslot = mt * 128 + arow;
  if (aslot >= Me) aslot = 0;
  const unsigned short* ap = act + (size_t)(ofs[e] + aslot) * INTERN;
  const unsigned short* w2 = wt2 + (size_t)e * HID * INTERN + (size_t)(nt * 128) * INTERN;
  f32x4 acc[4][4] = {};
  __syncthreads();

  for (int k0 = 0; k0 < INTERN; k0 += 32) {
    int4 aa = *reinterpret_cast<const int4*>(ap + k0 + acol);
    int4 ab = *reinterpret_cast<const int4*>(ap + k0 + acol + 8);
    const unsigned short* bp = w2 + (size_t)arow * INTERN + k0 + acol;
    int4 ba = *reinterpret_cast<const int4*>(bp);
    int4 bb = *reinterpret_cast<const int4*>(bp + 8);
    __syncthreads();
    *reinterpret_cast<int4*>(&As[arow][acol + 0]) = aa;
    *reinterpret_cast<int4*>(&As[arow][acol + 8]) = ab;
    *reinterpret_cast<int4*>(&Bs[arow][acol + 0]) = ba;
    *reinterpret_cast<int4*>(&Bs[arow][acol + 8]) = bb;
    __syncthreads();

    bf16x8 af[4], bf[4];
#pragma unroll
    for (int i = 0; i < 4; i++)
      af[i] = *reinterpret_cast<const bf16x8*>(&As[wm * 64 + i * 16 + l15][kq * 8]);
#pragma unroll
    for (int i = 0; i < 4; i++)
      bf[i] = *reinterpret_cast<const bf16x8*>(&Bs[wn * 64 + i * 16 + l15][kq * 8]);
#pragma unroll
    for (int mi = 0; mi < 4; mi++)
#pragma unroll
      for (int ni = 0; ni < 4; ni++)
        acc[mi][ni] = __builtin_amdgcn_mfma_f32_16x16x32_bf16(af[mi], bf[ni], acc[mi][ni], 0, 0, 0);
  }

#pragma unroll
  for (int mi = 0; mi < 4; mi++) {
#pragma unroll
    for (int ni = 0; ni < 4; ni++) {
      int coln = nt * 128 + wn * 64 + ni * 16 + l15;
#pragma unroll
      for (int r = 0; r < 4; r++) {
        int lrow = wm * 64 + mi * 16 + kq * 4 + r;
        if (mt * 128 + lrow < Me) {
          float v = acc[mi][ni][r] * rww[lrow];
          unsafeAtomicAdd(&out[(size_t)ridx[lrow] * HID + coln], v);
        }
      }
    }
  }
}

extern "C" void kernel_launch(void* const* d_in, const int* in_sizes, int n_in,
                              void* d_out, int out_size, void* d_ws, size_t ws_size,
                              hipStream_t stream) {
  const float* x     = (const float*)d_in[0];
  const float* probs = (const float*)d_in[1];
  const float* fc1   = (const float*)d_in[2];
  const float* fc2   = (const float*)d_in[3];
  const float* fc3   = (const float*)d_in[4];
  float* out = (float*)d_out;

  char* ws = (char*)d_ws;
  const size_t WSZ = (size_t)NEXP * HID * INTERN * 2;  // 67,108,864 B per weight tensor
  unsigned short* wt1 = (unsigned short*)(ws);
  unsigned short* wt3 = (unsigned short*)(ws + WSZ);
  unsigned short* wt2 = (unsigned short*)(ws + 2 * WSZ);
  unsigned short* act = (unsigned short*)(ws + 3 * WSZ);          // 16384*2048 bf16
  int*   brow = (int*)  (ws + 4 * WSZ);
  float* bw   = (float*)(ws + 4 * WSZ + (size_t)NEXP * CAP * 4);
  int*   cnt  = (int*)  (ws + 4 * WSZ + 2 * (size_t)NEXP * CAP * 4);
  int*   ofs  = (int*)  (ws + 4 * WSZ + 2 * (size_t)NEXP * CAP * 4 + 64);

  hipMemsetAsync(d_out, 0, (size_t)out_size * sizeof(float), stream);
  hipMemsetAsync(cnt, 0, 64, stream);

  transpose_cast_kernel<<<dim3(64, 64, 8), 256, 0, stream>>>(fc1, wt1);
  transpose_cast_kernel<<<dim3(64, 64, 8), 256, 0, stream>>>(fc3, wt3);
  transpose_cast_kernel<<<dim3(64, 64, 8), 256, 0, stream>>>(fc2, wt2);
  router_kernel<<<NROWS / 256, 256, 0, stream>>>(probs, cnt, brow, bw);
  offsets_kernel<<<1, 64, 0, stream>>>(cnt, ofs);
  gemm1_kernel<<<dim3(INTERN / 128, CAP / 128, NEXP), 256, 0, stream>>>(x, wt1, wt3, cnt, ofs, brow, act);
  gemm2_kernel<<<dim3(HID / 128, CAP / 128, NEXP), 256, 0, stream>>>(act, wt2, cnt, ofs, brow, bw, out);
}

// Round 2
// 865.958 us; speedup vs baseline: 1.1206x; 1.1206x over previous
//
#include <hip/hip_runtime.h>
#include <hip/hip_bf16.h>
#include <stdint.h>

#define NEXP 8
#define NROWS 8192
#define HID 2048
#define INTERN 2048
#define CAP 8192
#define KDIM 2048

typedef __attribute__((ext_vector_type(4))) float f32x4;
typedef __attribute__((ext_vector_type(8))) short bf16x8;

__device__ __forceinline__ unsigned short f2bf(float f) {
  union { float f; uint32_t u; } v; v.f = f;
  uint32_t u = v.u;
  uint32_t r = (u + 0x7fffu + ((u >> 16) & 1u)) >> 16;
  return (unsigned short)r;
}
__device__ __forceinline__ float bf2f(unsigned short u) {
  union { uint32_t u; float f; } v; v.u = (uint32_t)u << 16; return v.f;
}
__device__ __forceinline__ void gload16(const unsigned short* g, char* l) {
  __builtin_amdgcn_global_load_lds((const __attribute__((address_space(1))) void*)g,
                                   (__attribute__((address_space(3))) void*)l,
                                   16, 0, 0);
}

// ---------------- x fp32 -> bf16 ----------------
__global__ __launch_bounds__(256) void xcast_kernel(const float* __restrict__ x,
                                                    unsigned short* __restrict__ xb) {
  size_t i = ((size_t)blockIdx.x * 256 + threadIdx.x) * 8;
  size_t stride = (size_t)gridDim.x * 256 * 8;
  const size_t tot = (size_t)NROWS * HID;
  for (; i < tot; i += stride) {
    float4 a = *reinterpret_cast<const float4*>(x + i);
    float4 b = *reinterpret_cast<const float4*>(x + i + 4);
    unsigned short u[8];
    u[0] = f2bf(a.x); u[1] = f2bf(a.y); u[2] = f2bf(a.z); u[3] = f2bf(a.w);
    u[4] = f2bf(b.x); u[5] = f2bf(b.y); u[6] = f2bf(b.z); u[7] = f2bf(b.w);
    *reinterpret_cast<int4*>(xb + i) = *reinterpret_cast<const int4*>(u);
  }
}

// ---------------- router: top-2 of 8, renormalize, bucket per expert ----------------
__global__ void router_kernel(const float* __restrict__ probs,
                              int* __restrict__ cnt,
                              int* __restrict__ brow,
                              float* __restrict__ bw) {
  int row = blockIdx.x * blockDim.x + threadIdx.x;
  if (row >= NROWS) return;
  float p[8];
#pragma unroll
  for (int j = 0; j < 8; j++) p[j] = probs[row * 8 + j];
  int i1 = 0; float v1 = p[0];
#pragma unroll
  for (int j = 1; j < 8; j++) if (p[j] > v1) { v1 = p[j]; i1 = j; }
  int i2 = -1; float v2 = -1e30f;
#pragma unroll
  for (int j = 0; j < 8; j++) if (j != i1 && p[j] > v2) { v2 = p[j]; i2 = j; }
  float s = v1 + v2;
  float w1 = v1 / s, w2 = v2 / s;
  int pos1 = atomicAdd(&cnt[i1], 1);
  brow[i1 * CAP + pos1] = row; bw[i1 * CAP + pos1] = w1;
  int pos2 = atomicAdd(&cnt[i2], 1);
  brow[i2 * CAP + pos2] = row; bw[i2 * CAP + pos2] = w2;
}

__global__ void offsets_kernel(const int* __restrict__ cnt, int* __restrict__ ofs) {
  if (threadIdx.x == 0 && blockIdx.x == 0) {
    int a = 0;
    for (int e = 0; e < NEXP; e++) { ofs[e] = a; a += cnt[e]; }
  }
}

// ---------------- transpose+cast: [E][K][N] f32 -> [E][N][K] bf16, 64x64 tiles ----------------
__global__ __launch_bounds__(256) void transpose_cast_kernel(const float* __restrict__ src,
                                                             unsigned short* __restrict__ dst) {
  __shared__ float tile[64][65];
  const int e = blockIdx.z;
  const int k0 = blockIdx.y * 64;
  const int n0 = blockIdx.x * 64;
  const float* s = src + (size_t)e * KDIM * KDIM;
  unsigned short* d = dst + (size_t)e * KDIM * KDIM;
  const int t = threadIdx.x;
  const int rr = t >> 4, cc = (t & 15) * 4;
#pragma unroll
  for (int i = 0; i < 4; i++) {
    float4 v = *reinterpret_cast<const float4*>(s + (size_t)(k0 + rr + i * 16) * KDIM + n0 + cc);
    tile[rr + i * 16][cc + 0] = v.x; tile[rr + i * 16][cc + 1] = v.y;
    tile[rr + i * 16][cc + 2] = v.z; tile[rr + i * 16][cc + 3] = v.w;
  }
  __syncthreads();
  const int n = t >> 2, kk0 = (t & 3) * 16;
  unsigned short u[16];
#pragma unroll
  for (int j = 0; j < 16; j++) u[j] = f2bf(tile[kk0 + j][n]);
  *reinterpret_cast<int4*>(d + (size_t)(n0 + n) * KDIM + k0 + kk0 + 0) = *reinterpret_cast<const int4*>(&u[0]);
  *reinterpret_cast<int4*>(d + (size_t)(n0 + n) * KDIM + k0 + kk0 + 8) = *reinterpret_cast<const int4*>(&u[8]);
}

// ---------------- m97-structure GEMM, 128x128 tile, BK=32, global_load_lds, swizzled LDS ----
// EPI 0: hbuf[slot][col] = bf16(acc)                       (fc1 -> h1)
// EPI 1: hbuf[slot][col] = bf16(silu(h1)*acc)  in-place    (fc3 -> act)
// EPI 2: out[token][col] += rw * acc  (atomic scatter)     (fc2)
template <int EPI>
__global__ __launch_bounds__(256, 2)
void gemm_kernel(const unsigned short* __restrict__ A,
                 const unsigned short* __restrict__ W,
                 const int* __restrict__ cnt, const int* __restrict__ ofs,
                 const int* __restrict__ brow, const float* __restrict__ bw,
                 unsigned short* __restrict__ hbuf,
                 float* __restrict__ out) {
  const int e = blockIdx.z, mt = blockIdx.y, nt = blockIdx.x;
  const int Me = cnt[e];
  if (mt * 128 >= Me) return;
  __shared__ unsigned short As[128 * 32];
  __shared__ unsigned short Bs[128 * 32];
  __shared__ int ridx[128];
  __shared__ float rww[128];
  const int t = threadIdx.x, lane = t & 63, wave = t >> 6;
  const int oe = ofs[e];
  if (t < 128) {
    int sl = mt * 128 + t;
    int ok = sl < Me;
    ridx[t] = ok ? brow[e * CAP + sl] : 0;
    rww[t] = ok ? bw[e * CAP + sl] : 0.f;
  }
  __syncthreads();

  // staging: per-lane pre-swizzled global source (both-sides involution, rule #21)
  // LDS slot (lane&3) of row r holds global k-segment ((lane&3) - (r>>1)) & 3
  const int seg = ((lane & 3) - ((lane >> 3) & 3)) & 3;
  const int r0 = (wave * 2 + 0) * 16 + (lane >> 2);
  const int r1 = (wave * 2 + 1) * 16 + (lane >> 2);
  const unsigned short *gA0, *gA1;
  if (EPI == 2) {
    int s0 = mt * 128 + r0; if (s0 >= Me) s0 = 0;
    int s1 = mt * 128 + r1; if (s1 >= Me) s1 = 0;
    gA0 = A + (size_t)(oe + s0) * KDIM + seg * 8;
    gA1 = A + (size_t)(oe + s1) * KDIM + seg * 8;
  } else {
    gA0 = A + (size_t)ridx[r0] * KDIM + seg * 8;
    gA1 = A + (size_t)ridx[r1] * KDIM + seg * 8;
  }
  const unsigned short* Wb = W + (size_t)e * KDIM * KDIM;
  const unsigned short* gB0 = Wb + (size_t)(nt * 128 + r0) * KDIM + seg * 8;
  const unsigned short* gB1 = Wb + (size_t)(nt * 128 + r1) * KDIM + seg * 8;
  char* lA0 = (char*)As + (wave * 2 + 0) * 1024;
  char* lA1 = (char*)As + (wave * 2 + 1) * 1024;
  char* lB0 = (char*)Bs + (wave * 2 + 0) * 1024;
  char* lB1 = (char*)Bs + (wave * 2 + 1) * 1024;

  // fragment ds_read offsets (swizzled slot)
  const int wm = wave >> 1, wn = wave & 1;
  const int l15 = lane & 15, kq = lane >> 4;
  const int slotb = ((kq + ((l15 >> 1) & 3)) & 3) << 4;
  int offA[4], offB[4];
#pragma unroll
  for (int i = 0; i < 4; i++) {
    offA[i] = (wm * 64 + i * 16 + l15) * 64 + slotb;
    offB[i] = (wn * 64 + i * 16 + l15) * 64 + slotb;
  }
  f32x4 acc[4][4] = {};

  for (int k0 = 0; k0 < KDIM; k0 += 32) {
    gload16(gA0, lA0); gload16(gA1, lA1);
    gload16(gB0, lB0); gload16(gB1, lB1);
    gA0 += 32; gA1 += 32; gB0 += 32; gB1 += 32;
    __syncthreads();
    bf16x8 af[4], bf[4];
#pragma unroll
    for (int i = 0; i < 4; i++)
      af[i] = *reinterpret_cast<const bf16x8*>((const char*)As + offA[i]);
#pragma unroll
    for (int i = 0; i < 4; i++)
      bf[i] = *reinterpret_cast<const bf16x8*>((const char*)Bs + offB[i]);
#pragma unroll
    for (int mi = 0; mi < 4; mi++)
#pragma unroll
      for (int ni = 0; ni < 4; ni++)
        acc[mi][ni] = __builtin_amdgcn_mfma_f32_16x16x32_bf16(af[mi], bf[ni], acc[mi][ni], 0, 0, 0);
    __syncthreads();
  }

  const int slot0 = oe + mt * 128;
#pragma unroll
  for (int mi = 0; mi < 4; mi++) {
#pragma unroll
    for (int ni = 0; ni < 4; ni++) {
      const int coln = nt * 128 + wn * 64 + ni * 16 + l15;
#pragma unroll
      for (int r = 0; r < 4; r++) {
        const int lrow = wm * 64 + mi * 16 + kq * 4 + r;
        if (mt * 128 + lrow < Me) {
          if (EPI == 0) {
            hbuf[(size_t)(slot0 + lrow) * KDIM + coln] = f2bf(acc[mi][ni][r]);
          } else if (EPI == 1) {
            size_t idx = (size_t)(slot0 + lrow) * KDIM + coln;
            float h1 = bf2f(hbuf[idx]);
            float sig = 1.f / (1.f + __expf(-h1));
            hbuf[idx] = f2bf(h1 * sig * acc[mi][ni][r]);
          } else {
            float v = acc[mi][ni][r] * rww[lrow];
            unsafeAtomicAdd(&out[(size_t)ridx[lrow] * HID + coln], v);
          }
        }
      }
    }
  }
}

extern "C" void kernel_launch(void* const* d_in, const int* in_sizes, int n_in,
                              void* d_out, int out_size, void* d_ws, size_t ws_size,
                              hipStream_t stream) {
  const float* x     = (const float*)d_in[0];
  const float* probs = (const float*)d_in[1];
  const float* fc1   = (const float*)d_in[2];
  const float* fc2   = (const float*)d_in[3];
  const float* fc3   = (const float*)d_in[4];
  float* out = (float*)d_out;

  char* ws = (char*)d_ws;
  const size_t WSZ = (size_t)NEXP * HID * INTERN * 2;  // 64 MiB per weight tensor
  unsigned short* wt1 = (unsigned short*)(ws);
  unsigned short* wt3 = (unsigned short*)(ws + WSZ);
  unsigned short* wt2 = (unsigned short*)(ws + 2 * WSZ);
  unsigned short* h1  = (unsigned short*)(ws + 3 * WSZ);            // 16384 x 2048 bf16 (h1, then act)
  unsigned short* xb  = (unsigned short*)(ws + 4 * WSZ);            // 8192 x 2048 bf16 (32 MiB)
  char* rbase = ws + 4 * WSZ + (size_t)NROWS * HID * 2;
  int*   brow = (int*)  (rbase);
  float* bw   = (float*)(rbase + (size_t)NEXP * CAP * 4);
  int*   cnt  = (int*)  (rbase + 2 * (size_t)NEXP * CAP * 4);
  int*   ofs  = (int*)  (rbase + 2 * (size_t)NEXP * CAP * 4 + 64);

  hipMemsetAsync(d_out, 0, (size_t)out_size * sizeof(float), stream);
  hipMemsetAsync(cnt, 0, 64, stream);

  xcast_kernel<<<2048, 256, 0, stream>>>(x, xb);
  transpose_cast_kernel<<<dim3(32, 32, 8), 256, 0, stream>>>(fc1, wt1);
  transpose_cast_kernel<<<dim3(32, 32, 8), 256, 0, stream>>>(fc3, wt3);
  transpose_cast_kernel<<<dim3(32, 32, 8), 256, 0, stream>>>(fc2, wt2);
  router_kernel<<<NROWS / 256, 256, 0, stream>>>(probs, cnt, brow, bw);
  offsets_kernel<<<1, 64, 0, stream>>>(cnt, ofs);

  gemm_kernel<0><<<dim3(INTERN / 128, CAP / 128, NEXP), 256, 0, stream>>>(xb, wt1, cnt, ofs, brow, bw, h1, out);
  gemm_kernel<1><<<dim3(INTERN / 128, CAP / 128, NEXP), 256, 0, stream>>>(xb, wt3, cnt, ofs, brow, bw, h1, out);
  gemm_kernel<2><<<dim3(HID / 128, CAP / 128, NEXP), 256, 0, stream>>>(h1, wt2, cnt, ofs, brow, bw, h1, out);
}